// Round 9
// baseline (1011.561 us; speedup 1.0000x reference)
//
#include <hip/hip_runtime.h>
#include <math.h>

#define P_PLANE 262144  // 512*512 plane size

// ===== split-bf16 MFMA common machinery =====================================
typedef __attribute__((ext_vector_type(8))) short bf16x8;
typedef __attribute__((ext_vector_type(4))) float f32x4;
#define LDK 40   // ushort row stride for [row][k] LDS planes (80 B)

__device__ __forceinline__ unsigned short f2bf_rn(float x) {
    unsigned int u = __float_as_uint(x);
    unsigned int r = (u + 0x7FFFu + ((u >> 16) & 1u)) >> 16;
    return (unsigned short)r;
}
__device__ __forceinline__ float bf2f(unsigned short h) {
    return __uint_as_float(((unsigned int)h) << 16);
}
// split 8 floats into bf16 hi/lo, store one uint4 to each LDS target
__device__ __forceinline__ void split8(const float* v,
                                       unsigned short* Hs, unsigned short* Ls) {
    unsigned int hw[4], lw[4];
    #pragma unroll
    for (int t = 0; t < 4; ++t) {
        float a0 = v[2*t], a1 = v[2*t+1];
        unsigned short h0 = f2bf_rn(a0), h1 = f2bf_rn(a1);
        unsigned short l0 = f2bf_rn(a0 - bf2f(h0));
        unsigned short l1 = f2bf_rn(a1 - bf2f(h1));
        hw[t] = (unsigned int)h0 | ((unsigned int)h1 << 16);
        lw[t] = (unsigned int)l0 | ((unsigned int)l1 << 16);
    }
    uint4 h4 = {hw[0], hw[1], hw[2], hw[3]};
    uint4 l4 = {lw[0], lw[1], lw[2], lw[3]};
    *(uint4*)Hs = h4;
    *(uint4*)Ls = l4;
}

// ---------------------------------------------------------------------------
// GEMM + bias via split-bf16 MFMA: C[M,N] = A[M,K] @ W[K,N] + bias[N].
// 128x128 tile, BK=32, 4 waves (2x2, 64x64 each), 16x16x32 bf16 MFMA,
// Markidis 3-product, fp32 accumulate.
// Layout deps (shared with all MFMA kernels here):
//   C/D: col=lane&15, row=(lane>>4)*4+reg  [HW-verified, learn_hip m89/m91]
//   A/B: row/col = lane&15; identical k-slot map for A and B -> exact sum
//        over K by k-permutation invariance.
// M multiple of 128 (grid.y), N multiple of 128 (grid.x), K multiple of 32.
// ---------------------------------------------------------------------------
__global__ __launch_bounds__(256)
void gemm_bias_mfma_k(const float* __restrict__ A, const float* __restrict__ W,
                      const float* __restrict__ bias, float* __restrict__ C,
                      int N, int K)
{
    __shared__ unsigned short AsH[128 * LDK], AsL[128 * LDK];
    __shared__ unsigned short BsH[128 * LDK], BsL[128 * LDK];
    const int tid  = threadIdx.x;
    const int lane = tid & 63;
    const int wave = tid >> 6;
    const int wr = (wave >> 1) * 64, wc = (wave & 1) * 64;
    const int tm = blockIdx.y * 128, tn = blockIdx.x * 128;
    const int am = tid >> 1, ak = (tid & 1) << 4;     // A: row, k-half
    const int bn = tid & 127, bkg = (tid >> 7) << 4;  // B: col, k-half
    const int frow = lane & 15;
    const int kofs = (lane >> 4) << 3;

    f32x4 acc[4][4];
    #pragma unroll
    for (int a = 0; a < 4; ++a)
        #pragma unroll
        for (int b = 0; b < 4; ++b) acc[a][b] = (f32x4){0.f, 0.f, 0.f, 0.f};

    for (int k0 = 0; k0 < K; k0 += 32) {
        {   // ---- stage A [m][k], hi/lo split ----
            const float* ap = A + (size_t)(tm + am) * K + k0 + ak;
            float v[16];
            *(float4*)&v[0]  = *(const float4*)(ap);
            *(float4*)&v[4]  = *(const float4*)(ap + 4);
            *(float4*)&v[8]  = *(const float4*)(ap + 8);
            *(float4*)&v[12] = *(const float4*)(ap + 12);
            split8(&v[0], &AsH[am*LDK + ak],     &AsL[am*LDK + ak]);
            split8(&v[8], &AsH[am*LDK + ak + 8], &AsL[am*LDK + ak + 8]);
        }
        {   // ---- stage B, transpose [k][n] -> [n][k], hi/lo split ----
            const float* bp = W + (size_t)(k0 + bkg) * N + tn + bn;
            float v[16];
            #pragma unroll
            for (int t = 0; t < 16; ++t) v[t] = bp[(size_t)t * N];
            split8(&v[0], &BsH[bn*LDK + bkg],     &BsL[bn*LDK + bkg]);
            split8(&v[8], &BsH[bn*LDK + bkg + 8], &BsL[bn*LDK + bkg + 8]);
        }
        __syncthreads();
        bf16x8 ah[4], al[4], bh[4], bl[4];
        #pragma unroll
        for (int rb = 0; rb < 4; ++rb) {
            const int r = wr + rb*16 + frow;
            ah[rb] = *(const bf16x8*)&AsH[r*LDK + kofs];
            al[rb] = *(const bf16x8*)&AsL[r*LDK + kofs];
        }
        #pragma unroll
        for (int cb2 = 0; cb2 < 4; ++cb2) {
            const int n2 = wc + cb2*16 + frow;
            bh[cb2] = *(const bf16x8*)&BsH[n2*LDK + kofs];
            bl[cb2] = *(const bf16x8*)&BsL[n2*LDK + kofs];
        }
        #pragma unroll
        for (int rb = 0; rb < 4; ++rb)
            #pragma unroll
            for (int cb2 = 0; cb2 < 4; ++cb2) {
                acc[rb][cb2] = __builtin_amdgcn_mfma_f32_16x16x32_bf16(ah[rb], bh[cb2], acc[rb][cb2], 0, 0, 0);
                acc[rb][cb2] = __builtin_amdgcn_mfma_f32_16x16x32_bf16(ah[rb], bl[cb2], acc[rb][cb2], 0, 0, 0);
                acc[rb][cb2] = __builtin_amdgcn_mfma_f32_16x16x32_bf16(al[rb], bh[cb2], acc[rb][cb2], 0, 0, 0);
            }
        __syncthreads();
    }
    const int crow = (lane >> 4) * 4;
    #pragma unroll
    for (int cb2 = 0; cb2 < 4; ++cb2) {
        const int gc = tn + wc + cb2*16 + frow;
        const float bv = bias ? bias[gc] : 0.f;
        #pragma unroll
        for (int rb = 0; rb < 4; ++rb)
            #pragma unroll
            for (int v = 0; v < 4; ++v) {
                const int gr = tm + wr + rb*16 + crow + v;
                C[(size_t)gr * N + gc] = acc[rb][cb2][v] + bv;
            }
    }
}

// ---------------------------------------------------------------------------
// LayerNorm(1024) + joint L2-normalize (n0), in-place. One block per row.
// ---------------------------------------------------------------------------
__global__ __launch_bounds__(256)
void ln_norm_a_k(float* __restrict__ buf, const float* __restrict__ g,
                 const float* __restrict__ beta)
{
    __shared__ float red[16];
    const int row = blockIdx.x, tid = threadIdx.x;
    float* p = buf + (size_t)row * 1024;
    float4 x = *(const float4*)(p + tid * 4);
    float s1 = x.x + x.y + x.z + x.w;
    float s2 = x.x*x.x + x.y*x.y + x.z*x.z + x.w*x.w;
    #pragma unroll
    for (int off = 32; off; off >>= 1) {
        s1 += __shfl_down(s1, off);
        s2 += __shfl_down(s2, off);
    }
    if ((tid & 63) == 0) { red[(tid>>6)*2] = s1; red[(tid>>6)*2+1] = s2; }
    __syncthreads();
    float t1 = red[0] + red[2] + red[4] + red[6];
    float t2 = red[1] + red[3] + red[5] + red[7];
    float mean = t1 * (1.f/1024.f);
    float var  = t2 * (1.f/1024.f) - mean * mean;
    float rstd = 1.f / sqrtf(var + 1e-5f);
    float4 gv = *(const float4*)(g + tid * 4);
    float4 bv = *(const float4*)(beta + tid * 4);
    float4 e;
    e.x = (x.x - mean) * rstd * gv.x + bv.x;
    e.y = (x.y - mean) * rstd * gv.y + bv.y;
    e.z = (x.z - mean) * rstd * gv.z + bv.z;
    e.w = (x.w - mean) * rstd * gv.w + bv.w;
    float s3 = e.x*e.x + e.y*e.y + e.z*e.z + e.w*e.w;
    #pragma unroll
    for (int off = 32; off; off >>= 1) s3 += __shfl_down(s3, off);
    __syncthreads();               // everyone done reading red
    if ((tid & 63) == 0) red[tid>>6] = s3;
    __syncthreads();
    float inv = 1.f / sqrtf(red[0] + red[1] + red[2] + red[3] + 1e-10f);
    e.x *= inv; e.y *= inv; e.z *= inv; e.w *= inv;
    *(float4*)(p + tid * 4) = e;
}

// ---------------------------------------------------------------------------
// LayerNorm(512) + exact GELU, in-place. One block (128 thr) per row.
// ---------------------------------------------------------------------------
__global__ __launch_bounds__(128)
void ln_gelu_k(float* __restrict__ buf, const float* __restrict__ g,
               const float* __restrict__ beta)
{
    __shared__ float red[8];
    const int row = blockIdx.x, tid = threadIdx.x;
    float* p = buf + (size_t)row * 512;
    float4 x = *(const float4*)(p + tid * 4);
    float s1 = x.x + x.y + x.z + x.w;
    float s2 = x.x*x.x + x.y*x.y + x.z*x.z + x.w*x.w;
    #pragma unroll
    for (int off = 32; off; off >>= 1) {
        s1 += __shfl_down(s1, off);
        s2 += __shfl_down(s2, off);
    }
    if ((tid & 63) == 0) { red[(tid>>6)*2] = s1; red[(tid>>6)*2+1] = s2; }
    __syncthreads();
    float t1 = red[0] + red[2];
    float t2 = red[1] + red[3];
    float mean = t1 * (1.f/512.f);
    float var  = t2 * (1.f/512.f) - mean * mean;
    float rstd = 1.f / sqrtf(var + 1e-5f);
    float4 gv = *(const float4*)(g + tid * 4);
    float4 bv = *(const float4*)(beta + tid * 4);
    float e[4];
    e[0] = (x.x - mean) * rstd * gv.x + bv.x;
    e[1] = (x.y - mean) * rstd * gv.y + bv.y;
    e[2] = (x.z - mean) * rstd * gv.z + bv.z;
    e[3] = (x.w - mean) * rstd * gv.w + bv.w;
    float4 o;
    float* op = &o.x;
    #pragma unroll
    for (int q = 0; q < 4; ++q)
        op[q] = 0.5f * e[q] * (1.f + erff(e[q] * 0.70710678118654752f));
    *(float4*)(p + tid * 4) = o;
}

// ---------------------------------------------------------------------------
// logits = feat @ Wa + ba ; w = softmax; sw = sqrt(w). One 64-lane wave/row.
// ---------------------------------------------------------------------------
__global__ __launch_bounds__(256)
void attn_w_k(const float* __restrict__ feat, const float* __restrict__ Wa,
              const float* __restrict__ ba, float* __restrict__ sw)
{
    const int row  = blockIdx.x * 4 + (threadIdx.x >> 6);
    const int lane = threadIdx.x & 63;
    const float* f = feat + (size_t)row * 512;
    float acc[8] = {};
    #pragma unroll
    for (int it = 0; it < 8; ++it) {
        int k = lane + it * 64;
        float fv = f[k];
        float4 w0 = *(const float4*)(Wa + (size_t)k * 8);
        float4 w1 = *(const float4*)(Wa + (size_t)k * 8 + 4);
        acc[0] = fmaf(fv, w0.x, acc[0]); acc[1] = fmaf(fv, w0.y, acc[1]);
        acc[2] = fmaf(fv, w0.z, acc[2]); acc[3] = fmaf(fv, w0.w, acc[3]);
        acc[4] = fmaf(fv, w1.x, acc[4]); acc[5] = fmaf(fv, w1.y, acc[5]);
        acc[6] = fmaf(fv, w1.z, acc[6]); acc[7] = fmaf(fv, w1.w, acc[7]);
    }
    #pragma unroll
    for (int off = 32; off; off >>= 1)
        #pragma unroll
        for (int o = 0; o < 8; ++o) acc[o] += __shfl_down(acc[o], off);
    if (lane == 0) {
        float l[8], mx = -1e30f;
        #pragma unroll
        for (int o = 0; o < 8; ++o) { l[o] = acc[o] + ba[o]; mx = fmaxf(mx, l[o]); }
        float s = 0.f;
        #pragma unroll
        for (int o = 0; o < 8; ++o) { l[o] = expf(l[o] - mx); s += l[o]; }
        float invs = 1.f / s;
        #pragma unroll
        for (int o = 0; o < 8; ++o) sw[(size_t)row * 8 + o] = sqrtf(l[o] * invs);
    }
}

// ---------------------------------------------------------------------------
// X = i*H / 2^s, H = (Ar+Ar^T) + i(Ai-Ai^T)  =>  Xr = (Ai^T - Ai)*sc, Xi = (Ar+Ar^T)*sc
// Complex batch layout: [c][part(0=r,1=i)][512][512]
// ---------------------------------------------------------------------------
__global__ void build_x_k(const float* __restrict__ Ar_in, const float* __restrict__ Ai_in,
                          float* __restrict__ X, float sc)
{
    const int c = blockIdx.z;
    const int j = blockIdx.x * 32 + threadIdx.x;
    const int i = blockIdx.y * 8  + threadIdx.y;
    const size_t ij = (size_t)c * P_PLANE + (size_t)i * 512 + j;
    const size_t ji = (size_t)c * P_PLANE + (size_t)j * 512 + i;
    float ai_ij = Ai_in[ij], ai_ji = Ai_in[ji];
    float ar_ij = Ar_in[ij], ar_ji = Ar_in[ji];
    size_t base = (size_t)c * 2 * P_PLANE + (size_t)i * 512 + j;
    X[base]           = (ai_ji - ai_ij) * sc;
    X[base + P_PLANE] = (ar_ij + ar_ji) * sc;
}

// ---------------------------------------------------------------------------
// Fused Paterson-Stockmeyer coefficient pass (one read of X..X4, two writes):
//   o1 = c4 I + c5 X + c6 X2 + c7 X3 + c8 X4   (A1 + c8*X4)
//   o2 = I + X + X2/2 + X3/6                   (A0)
// Identity added to real planes' diagonals only. o1/o2 distinct from inputs.
// ---------------------------------------------------------------------------
__global__ void axpy2_k(float* __restrict__ o1, float* __restrict__ o2,
                        const float* __restrict__ X, const float* __restrict__ X2,
                        const float* __restrict__ X3, const float* __restrict__ X4)
{
    size_t idx = (size_t)blockIdx.x * 256 + threadIdx.x;
    float x = X[idx], x2 = X2[idx], x3 = X3[idx], x4 = X4[idx];
    float v1 = (1.f/120.f)*x + (1.f/720.f)*x2 + (1.f/5040.f)*x3 + (1.f/40320.f)*x4;
    float v2 = x + 0.5f*x2 + (1.f/6.f)*x3;
    size_t part = (idx >> 18) & 1;
    size_t pos  = idx & (P_PLANE - 1);
    if (part == 0 && (pos >> 9) == (pos & 511)) { v1 += 1.f/24.f; v2 += 1.f; }
    o1[idx] = v1;
    o2[idx] = v2;
}

// ---------------------------------------------------------------------------
// Batched complex GEMM via split-bf16 MFMA, 512x512x512, batch=8 (blockIdx.z).
// C = A@B (+ D if D != null). D may alias C (same-thread read-then-write).
// Cr = Ar·Br − Ai·Bi ; Ci = Ar·Bi + Ai·Br.  The −Ai·Bi term is realized as
// Ai·(−Bi) with −Bi formed by sign-XOR on the bf16 fragments (exact:
// lo(−x) = −lo(x) under RTNE split), keeping only 2 accumulator planes.
// 64x64 tile, BK=32, 4 waves (2x2, 32x32 each), 16x16x32 bf16 MFMA,
// 12 MFMA per fragment pair (3-product Markidis x 4 real products).
// LDS: 8 planes x 64xLDK ushorts = 40 KB.
// ---------------------------------------------------------------------------
__global__ __launch_bounds__(256)
void cgemm_mfma_k(const float* __restrict__ A, const float* __restrict__ B,
                  float* C, const float* D)
{
    __shared__ unsigned short ArHs[64*LDK], ArLs[64*LDK], AiHs[64*LDK], AiLs[64*LDK];
    __shared__ unsigned short BrHs[64*LDK], BrLs[64*LDK], BiHs[64*LDK], BiLs[64*LDK];
    const int c = blockIdx.z;
    const size_t cs = (size_t)c * 2 * P_PLANE;
    const float* Arp = A + cs; const float* Aip = Arp + P_PLANE;
    const float* Brp = B + cs; const float* Bip = Brp + P_PLANE;
    const int tid  = threadIdx.x;
    const int lane = tid & 63;
    const int wave = tid >> 6;
    const int wr  = (wave >> 1) * 32, wc2 = (wave & 1) * 32;
    const int tm = blockIdx.y * 64, tn = blockIdx.x * 64;
    const int ar0 = tid >> 2, aq = (tid & 3) * 8;
    const int bn = tid & 63, bq = (tid >> 6) * 8;
    const int frow = lane & 15;
    const int kofs = (lane >> 4) << 3;
    const bf16x8 SGN = {(short)0x8000,(short)0x8000,(short)0x8000,(short)0x8000,
                        (short)0x8000,(short)0x8000,(short)0x8000,(short)0x8000};

    f32x4 accR[2][2], accI[2][2];
    #pragma unroll
    for (int a = 0; a < 2; ++a)
        #pragma unroll
        for (int b = 0; b < 2; ++b) {
            accR[a][b] = (f32x4){0.f, 0.f, 0.f, 0.f};
            accI[a][b] = (f32x4){0.f, 0.f, 0.f, 0.f};
        }

    for (int k0 = 0; k0 < 512; k0 += 32) {
        {   // ---- stage A tile (rows, [m][k]), real + imag, hi/lo split ----
            const float* pr = Arp + (size_t)(tm + ar0) * 512 + k0 + aq;
            const float* pi = Aip + (size_t)(tm + ar0) * 512 + k0 + aq;
            float vr[8], vi[8];
            *(float4*)&vr[0] = *(const float4*)pr;
            *(float4*)&vr[4] = *(const float4*)(pr + 4);
            *(float4*)&vi[0] = *(const float4*)pi;
            *(float4*)&vi[4] = *(const float4*)(pi + 4);
            split8(vr, &ArHs[ar0*LDK + aq], &ArLs[ar0*LDK + aq]);
            split8(vi, &AiHs[ar0*LDK + aq], &AiLs[ar0*LDK + aq]);
        }
        {   // ---- stage B tile (transpose to [n][k]), real + imag ----
            const float* pr = Brp + (size_t)(k0 + bq) * 512 + tn + bn;
            const float* pi = Bip + (size_t)(k0 + bq) * 512 + tn + bn;
            float vr[8], vi[8];
            #pragma unroll
            for (int t = 0; t < 8; ++t) {
                vr[t] = pr[(size_t)t * 512];
                vi[t] = pi[(size_t)t * 512];
            }
            split8(vr, &BrHs[bn*LDK + bq], &BrLs[bn*LDK + bq]);
            split8(vi, &BiHs[bn*LDK + bq], &BiLs[bn*LDK + bq]);
        }
        __syncthreads();
        // ---- fragments ----
        bf16x8 arh[2], arl[2], aih[2], ail[2];
        #pragma unroll
        for (int rb = 0; rb < 2; ++rb) {
            const int r = wr + rb*16 + frow;
            arh[rb] = *(const bf16x8*)&ArHs[r*LDK + kofs];
            arl[rb] = *(const bf16x8*)&ArLs[r*LDK + kofs];
            aih[rb] = *(const bf16x8*)&AiHs[r*LDK + kofs];
            ail[rb] = *(const bf16x8*)&AiLs[r*LDK + kofs];
        }
        bf16x8 brh[2], brl[2], bih[2], bil[2], nbh[2], nbl[2];
        #pragma unroll
        for (int cb = 0; cb < 2; ++cb) {
            const int n2 = wc2 + cb*16 + frow;
            brh[cb] = *(const bf16x8*)&BrHs[n2*LDK + kofs];
            brl[cb] = *(const bf16x8*)&BrLs[n2*LDK + kofs];
            bih[cb] = *(const bf16x8*)&BiHs[n2*LDK + kofs];
            bil[cb] = *(const bf16x8*)&BiLs[n2*LDK + kofs];
            nbh[cb] = bih[cb] ^ SGN;   // -Bi hi
            nbl[cb] = bil[cb] ^ SGN;   // -Bi lo
        }
        // ---- MFMA: 12 per fragment pair ----
        #pragma unroll
        for (int rb = 0; rb < 2; ++rb)
            #pragma unroll
            for (int cb = 0; cb < 2; ++cb) {
                accR[rb][cb] = __builtin_amdgcn_mfma_f32_16x16x32_bf16(arh[rb], brh[cb], accR[rb][cb], 0, 0, 0);
                accR[rb][cb] = __builtin_amdgcn_mfma_f32_16x16x32_bf16(arh[rb], brl[cb], accR[rb][cb], 0, 0, 0);
                accR[rb][cb] = __builtin_amdgcn_mfma_f32_16x16x32_bf16(arl[rb], brh[cb], accR[rb][cb], 0, 0, 0);
                accR[rb][cb] = __builtin_amdgcn_mfma_f32_16x16x32_bf16(aih[rb], nbh[cb], accR[rb][cb], 0, 0, 0);
                accR[rb][cb] = __builtin_amdgcn_mfma_f32_16x16x32_bf16(aih[rb], nbl[cb], accR[rb][cb], 0, 0, 0);
                accR[rb][cb] = __builtin_amdgcn_mfma_f32_16x16x32_bf16(ail[rb], nbh[cb], accR[rb][cb], 0, 0, 0);
                accI[rb][cb] = __builtin_amdgcn_mfma_f32_16x16x32_bf16(arh[rb], bih[cb], accI[rb][cb], 0, 0, 0);
                accI[rb][cb] = __builtin_amdgcn_mfma_f32_16x16x32_bf16(arh[rb], bil[cb], accI[rb][cb], 0, 0, 0);
                accI[rb][cb] = __builtin_amdgcn_mfma_f32_16x16x32_bf16(arl[rb], bih[cb], accI[rb][cb], 0, 0, 0);
                accI[rb][cb] = __builtin_amdgcn_mfma_f32_16x16x32_bf16(aih[rb], brh[cb], accI[rb][cb], 0, 0, 0);
                accI[rb][cb] = __builtin_amdgcn_mfma_f32_16x16x32_bf16(aih[rb], brl[cb], accI[rb][cb], 0, 0, 0);
                accI[rb][cb] = __builtin_amdgcn_mfma_f32_16x16x32_bf16(ail[rb], brh[cb], accI[rb][cb], 0, 0, 0);
            }
        __syncthreads();
    }
    // ---- epilogue per verified C/D map ----
    float* Cr = C + cs; float* Ci = Cr + P_PLANE;
    const float* Dp = D ? (D + cs) : (const float*)0;
    const int crow = (lane >> 4) * 4;
    #pragma unroll
    for (int rb = 0; rb < 2; ++rb)
        #pragma unroll
        for (int cb = 0; cb < 2; ++cb)
            #pragma unroll
            for (int v = 0; v < 4; ++v) {
                const int gr = tm + wr + rb*16 + crow + v;
                const int gc = tn + wc2 + cb*16 + frow;
                float xr = accR[rb][cb][v], xi = accI[rb][cb][v];
                if (Dp) {
                    xr += Dp[(size_t)gr * 512 + gc];
                    xi += Dp[P_PLANE + (size_t)gr * 512 + gc];
                }
                Cr[(size_t)gr * 512 + gc] = xr;
                Ci[(size_t)gr * 512 + gc] = xi;
            }
}

// ---------------------------------------------------------------------------
// Stage E via split-bf16 MFMA (Markidis 3-product, fp32 accumulate).
// out[b,j] = sum_{c,i} (sw[b,c]*s[b,i]) * U[c][i][j];  M=8192,N=512,K=4096.
// 128x128 tile, BK=32, 4 waves (2x2, 64x64 each), 16x16x32 bf16 MFMA.
// blockIdx.z: 0 -> (s_r, Ur, tr), 1 -> (s_i, Ui, ti).
// ---------------------------------------------------------------------------
__global__ __launch_bounds__(256)
void gemm_mix_mfma_k(const float* __restrict__ enc,
                     const float* __restrict__ sw,
                     const float* __restrict__ Up,
                     float* __restrict__ tr, float* __restrict__ ti)
{
    __shared__ unsigned short AsH[128 * LDK], AsL[128 * LDK];
    __shared__ unsigned short BsH[128 * LDK], BsL[128 * LDK];
    const int z = blockIdx.z;
    const int soff = z << 9;
    const float* Upz = Up + (size_t)z * P_PLANE;
    float* outp = z ? ti : tr;
    const int tid  = threadIdx.x;
    const int lane = tid & 63;
    const int wave = tid >> 6;
    const int wr = (wave >> 1) * 64, wc = (wave & 1) * 64;
    const int tm = blockIdx.y * 128, tn = blockIdx.x * 128;
    const int am = tid >> 1, ak = (tid & 1) << 4;
    const int bn = tid & 127, bkg = (tid >> 7) << 4;
    const int frow = lane & 15;
    const int kofs = (lane >> 4) << 3;   // ushort offset 0/8/16/24

    f32x4 acc[4][4];
    #pragma unroll
    for (int a = 0; a < 4; ++a)
        #pragma unroll
        for (int b = 0; b < 4; ++b) acc[a][b] = (f32x4){0.f, 0.f, 0.f, 0.f};

    for (int k0 = 0; k0 < 4096; k0 += 32) {
        const int c = k0 >> 9;
        const int ibase = k0 & 511;     // BK=32 divides 512: c fixed per tile
        // ---- stage A (scaled enc slice), split hi/lo ----
        {
            float sc = sw[(size_t)(tm + am) * 8 + c];
            const float* ap = enc + (size_t)(tm + am) * 1024 + soff + ibase + ak;
            float v[16];
            *(float4*)&v[0]  = *(const float4*)(ap);
            *(float4*)&v[4]  = *(const float4*)(ap + 4);
            *(float4*)&v[8]  = *(const float4*)(ap + 8);
            *(float4*)&v[12] = *(const float4*)(ap + 12);
            #pragma unroll
            for (int t = 0; t < 16; ++t) v[t] *= sc;
            split8(&v[0], &AsH[am*LDK + ak],     &AsL[am*LDK + ak]);
            split8(&v[8], &AsH[am*LDK + ak + 8], &AsL[am*LDK + ak + 8]);
        }
        // ---- stage B (U plane), transpose to [n][k], split hi/lo ----
        {
            const float* bp = Upz + (size_t)c * 2 * P_PLANE
                                  + (size_t)(ibase + bkg) * 512 + tn + bn;
            float v[16];
            #pragma unroll
            for (int t = 0; t < 16; ++t) v[t] = bp[(size_t)t * 512];
            split8(&v[0], &BsH[bn*LDK + bkg],     &BsL[bn*LDK + bkg]);
            split8(&v[8], &BsH[bn*LDK + bkg + 8], &BsL[bn*LDK + bkg + 8]);
        }
        __syncthreads();
        // ---- fragments + MFMA ----
        bf16x8 ah[4], al[4], bh[4], bl[4];
        #pragma unroll
        for (int rb = 0; rb < 4; ++rb) {
            const int r = wr + rb*16 + frow;
            ah[rb] = *(const bf16x8*)&AsH[r*LDK + kofs];
            al[rb] = *(const bf16x8*)&AsL[r*LDK + kofs];
        }
        #pragma unroll
        for (int cb2 = 0; cb2 < 4; ++cb2) {
            const int n2 = wc + cb2*16 + frow;
            bh[cb2] = *(const bf16x8*)&BsH[n2*LDK + kofs];
            bl[cb2] = *(const bf16x8*)&BsL[n2*LDK + kofs];
        }
        #pragma unroll
        for (int rb = 0; rb < 4; ++rb)
            #pragma unroll
            for (int cb2 = 0; cb2 < 4; ++cb2) {
                acc[rb][cb2] = __builtin_amdgcn_mfma_f32_16x16x32_bf16(ah[rb], bh[cb2], acc[rb][cb2], 0, 0, 0);
                acc[rb][cb2] = __builtin_amdgcn_mfma_f32_16x16x32_bf16(ah[rb], bl[cb2], acc[rb][cb2], 0, 0, 0);
                acc[rb][cb2] = __builtin_amdgcn_mfma_f32_16x16x32_bf16(al[rb], bh[cb2], acc[rb][cb2], 0, 0, 0);
            }
        __syncthreads();
    }
    // ---- C write per verified C/D map ----
    const int crow = (lane >> 4) * 4;
    #pragma unroll
    for (int rb = 0; rb < 4; ++rb)
        #pragma unroll
        for (int cb2 = 0; cb2 < 4; ++cb2)
            #pragma unroll
            for (int v = 0; v < 4; ++v) {
                const int gr = tm + wr + rb*16 + crow + v;
                const int gc = tn + wc + cb2*16 + frow;
                outp[(size_t)gr * 512 + gc] = acc[rb][cb2][v];
            }
}

// ---------------------------------------------------------------------------
// probs[b,o] = ((tr@basis)^2 + (ti@basis)^2) / (||tr||^2+||ti||^2+1e-10)
// One block (128 thr) per row; tr/ti rows staged in LDS.
// ---------------------------------------------------------------------------
__global__ __launch_bounds__(128)
void finalize_k(const float* __restrict__ tr, const float* __restrict__ ti,
                const float* __restrict__ basis, float* __restrict__ out)
{
    __shared__ float trS[512], tiS[512];
    __shared__ float red[2];
    const int row = blockIdx.x, tid = threadIdx.x;
    float4 a = *(const float4*)(tr + (size_t)row * 512 + tid * 4);
    float4 b = *(const float4*)(ti + (size_t)row * 512 + tid * 4);
    *(float4*)&trS[tid * 4] = a;
    *(float4*)&tiS[tid * 4] = b;
    float loc = a.x*a.x + a.y*a.y + a.z*a.z + a.w*a.w
              + b.x*b.x + b.y*b.y + b.z*b.z + b.w*b.w;
    #pragma unroll
    for (int off = 32; off; off >>= 1) loc += __shfl_down(loc, off);
    if ((tid & 63) == 0) red[tid >> 6] = loc;
    __syncthreads();
    const float n1sq = red[0] + red[1] + 1e-10f;
    float accR = 0.f, accI = 0.f;
    #pragma unroll 8
    for (int j = 0; j < 512; ++j) {
        float bv = basis[(size_t)j * 128 + tid];
        accR = fmaf(trS[j], bv, accR);
        accI = fmaf(tiS[j], bv, accI);
    }
    out[(size_t)row * 128 + tid] = (accR * accR + accI * accI) / n1sq;
}

// ---------------------------------------------------------------------------
// Workspace layout (floats), live-range-safe aliasing (~128.3 MB):
//   enc: 8192*1024                     (Stage A -> Stage E)
//   sw : 8192*8                        (Stage C -> Stage E)
//   X,X2,X3,X4,U1,U2 complex buffers   (Stage D; feat aliases X since feat is
//                                       dead before build_x_k; tr/ti alias
//                                       X2/X3 since only U2 and X survive the
//                                       squaring chain, result lands in U2)
// exp(iH): s=4 scaling + degree-8 Taylor via Paterson-Stockmeyer:
//   p8 = A0 + X4@(A1 + c8*X4),  A0 = I+X+X2/2+X3/6,
//   A1+c8*X4 = c4 I + c5 X + c6 X2 + c7 X3 + c8 X4 (axpy2_k writes both)
//   truncation ~1.8e-8 (||X||<=0.57); split-bf16 GEMM adds ~1e-5 rel per
//   product -> ~1e-4 rel on U after 4 squarings, well below tolerance.
// ---------------------------------------------------------------------------
extern "C" void kernel_launch(void* const* d_in, const int* in_sizes, int n_in,
                              void* d_out, int out_size, void* d_ws, size_t ws_size,
                              hipStream_t stream)
{
    (void)in_sizes; (void)n_in; (void)out_size; (void)ws_size;
    const float* obs    = (const float*)d_in[0];
    const float* ctx    = (const float*)d_in[1];
    const float* Wb     = (const float*)d_in[2];
    const float* bb     = (const float*)d_in[3];
    const float* gb     = (const float*)d_in[4];
    const float* betab  = (const float*)d_in[5];
    const float* Wc     = (const float*)d_in[6];
    const float* bc     = (const float*)d_in[7];
    const float* gc     = (const float*)d_in[8];
    const float* betac  = (const float*)d_in[9];
    const float* Wa     = (const float*)d_in[10];
    const float* ba     = (const float*)d_in[11];
    const float* A_real = (const float*)d_in[12];
    const float* A_imag = (const float*)d_in[13];
    const float* basis  = (const float*)d_in[14];
    float* out = (float*)d_out;

    float* ws = (float*)d_ws;
    const size_t CB = (size_t)8 * 2 * P_PLANE;     // one complex batch buffer (4M floats)
    float* enc  = ws;                              // 8192*1024
    float* sw   = enc + (size_t)8192 * 1024;       // 8192*8
    float* X    = sw  + (size_t)8192 * 8;
    float* X2   = X   + CB;
    float* X3   = X2  + CB;
    float* X4   = X3  + CB;
    float* U1   = X4  + CB;
    float* U2   = U1  + CB;
    float* feat = X;    // feat (8192*512 = 4M floats) dead before build_x_k
    float* tr   = X2;   // written only after squaring chain (U2/X are the
    float* ti   = X3;   // only live exp-chain buffers by then)

    // ---- Stage A: enc = normalize(LN(obs @ Wb + bb)) ----
    gemm_bias_mfma_k<<<dim3(1024/128, 8192/128), 256, 0, stream>>>(obs, Wb, bb, enc, 1024, 1024);
    ln_norm_a_k<<<8192, 256, 0, stream>>>(enc, gb, betab);

    // ---- Stage B: feat = gelu(LN(ctx @ Wc + bc)) ----
    gemm_bias_mfma_k<<<dim3(512/128, 8192/128), 256, 0, stream>>>(ctx, Wc, bc, feat, 512, 1024);
    ln_gelu_k<<<8192, 128, 0, stream>>>(feat, gc, betac);

    // ---- Stage C: sw = sqrt(softmax(feat @ Wa + ba)) ----
    attn_w_k<<<2048, 256, 0, stream>>>(feat, Wa, ba, sw);

    // ---- Stage D: U = exp(iH), s=4 + degree-8 Paterson-Stockmeyer (MFMA) ----
    build_x_k<<<dim3(16, 64, 8), dim3(32, 8), 0, stream>>>(A_real, A_imag, X, 1.f/16.f);
    const dim3 gc9(8, 8, 8);   // 64x64 tiles over 512x512, 8 batch
    cgemm_mfma_k<<<gc9, 256, 0, stream>>>(X,  X,  X2, nullptr);   // X2 = X^2
    cgemm_mfma_k<<<gc9, 256, 0, stream>>>(X2, X,  X3, nullptr);   // X3 = X^3
    cgemm_mfma_k<<<gc9, 256, 0, stream>>>(X2, X2, X4, nullptr);   // X4 = X^4
    axpy2_k<<<16384, 256, 0, stream>>>(U1, U2, X, X2, X3, X4);    // U1 = A1+c8X4, U2 = A0
    cgemm_mfma_k<<<gc9, 256, 0, stream>>>(X4, U1, U2, U2);        // U2 = X4@U1 + A0 = p8(X)
    float* Pp = U2; float* Qp = X;
    for (int t = 0; t < 4; ++t) {                                 // 4 squarings
        cgemm_mfma_k<<<gc9, 256, 0, stream>>>(Pp, Pp, Qp, nullptr);
        float* tmp = Pp; Pp = Qp; Qp = tmp;
    }
    // Even number of swaps: Pp == U2 holds exp(iH).

    // ---- Stage E (merged, MFMA): tr/ti = [sw (x) s] @ U planes ----
    gemm_mix_mfma_k<<<dim3(512/128, 8192/128, 2), 256, 0, stream>>>(enc, sw, Pp, tr, ti);

    // ---- Final: probs ----
    finalize_k<<<8192, 128, 0, stream>>>(tr, ti, basis, out);
}